// Round 1
// baseline (2033.538 us; speedup 1.0000x reference)
//
#include <hip/hip_runtime.h>

#define NUQ 50000
#define NIQ 50000
#define DQ 256
#define NTOT 100000
#define LALPHA 0.2f

// ---------------------------------------------------------------------------
// SpMM: one wave (64 lanes) per output row; lane covers 4 of 256 dims (float4).
// rows[] is sorted -> binary search row extents. Optionally multiply result
// elementwise by mul[row][:] (the l_spmm * ebs fusion). Writes into a
// [n_rows, 512] scratch at column offset col_off.
// ---------------------------------------------------------------------------
__global__ __launch_bounds__(256) void spmm_kernel(
    const int* __restrict__ rows, const int* __restrict__ cols,
    const float* __restrict__ vals, int nnz,
    const float* __restrict__ src,          // [NTOT, 256] current ebs
    const float* __restrict__ mul,          // nullptr or [n_rows,256] (ebs slice)
    float* __restrict__ out,                // [n_rows, 512] scratch
    int n_rows, int col_off)
{
    int wave = threadIdx.x >> 6;
    int lane = threadIdx.x & 63;
    int row  = blockIdx.x * 4 + wave;
    if (row >= n_rows) return;

    // lower_bound(rows, row) -> start ; lower_bound(rows, row+1) -> end
    int lo = 0, hi = nnz;
    while (lo < hi) { int mid = (lo + hi) >> 1; if (rows[mid] < row) lo = mid + 1; else hi = mid; }
    int start = lo;
    hi = nnz;
    while (lo < hi) { int mid = (lo + hi) >> 1; if (rows[mid] < row + 1) lo = mid + 1; else hi = mid; }
    int end = lo;

    float4 acc = {0.f, 0.f, 0.f, 0.f};
    for (int e = start; e < end; ++e) {
        int   c = cols[e];
        float v = vals[e];
        float4 s = ((const float4*)(src + (size_t)c * DQ))[lane];
        acc.x = fmaf(v, s.x, acc.x);
        acc.y = fmaf(v, s.y, acc.y);
        acc.z = fmaf(v, s.z, acc.z);
        acc.w = fmaf(v, s.w, acc.w);
    }
    if (mul) {
        float4 m = ((const float4*)(mul + (size_t)row * DQ))[lane];
        acc.x *= m.x; acc.y *= m.y; acc.z *= m.z; acc.w *= m.w;
    }
    ((float4*)(out + (size_t)row * 512 + col_off))[lane] = acc;
}

// ---------------------------------------------------------------------------
// Fused GEMM + leaky_relu:  out[M,256] = leaky( A[M,512] @ [Ws;Wd][512,256] )
// BM=64, BN=64, BK=16; 256 threads; 4x4 register micro-tile per thread.
// As stored transposed [k][m] so the inner loop reads are float4 per thread.
// ---------------------------------------------------------------------------
__global__ __launch_bounds__(256) void gemm_leaky_kernel(
    const float* __restrict__ A,    // [M, 512] row-major scratch
    const float* __restrict__ Ws,   // [256,256] row-major (k rows 0..255)
    const float* __restrict__ Wd,   // [256,256] row-major (k rows 256..511)
    float* __restrict__ out,        // [M, 256] destination (already offset)
    int M)
{
    __shared__ float As[16][64];
    __shared__ float Bs[16][64];

    const int tid  = threadIdx.x;
    const int tx   = tid & 15;         // 0..15 -> 4 cols each
    const int ty   = tid >> 4;         // 0..15 -> 4 rows each
    const int row0 = blockIdx.x * 64;
    const int col0 = blockIdx.y * 64;

    // staging indices
    const int ar = tid >> 2;           // 0..63 (A row within tile)
    const int ak = (tid & 3) * 4;      // 0,4,8,12 (k offset, float4)
    const int bk = tid >> 4;           // 0..15 (B k within tile)
    const int bc = (tid & 15) * 4;     // 0..60 (B col, float4)

    float acc[4][4] = {};

    const int arow = row0 + ar;
    const float* Arow = A + (size_t)arow * 512;

    for (int kt = 0; kt < 32; ++kt) {
        const int k0 = kt * 16;

        // stage A tile (transposed into LDS)
        float4 av = {0.f, 0.f, 0.f, 0.f};
        if (arow < M) av = *(const float4*)(Arow + k0 + ak);
        As[ak + 0][ar] = av.x;
        As[ak + 1][ar] = av.y;
        As[ak + 2][ar] = av.z;
        As[ak + 3][ar] = av.w;

        // stage B tile (pick Ws vs Wd half; k-tiles never straddle 256)
        const float* Bbase = (k0 < 256) ? (Ws + (size_t)k0 * 256)
                                        : (Wd + (size_t)(k0 - 256) * 256);
        float4 bv = *(const float4*)(Bbase + (size_t)bk * 256 + col0 + bc);
        *(float4*)&Bs[bk][bc] = bv;

        __syncthreads();

        #pragma unroll
        for (int kk = 0; kk < 16; ++kk) {
            float4 a4 = *(const float4*)&As[kk][ty * 4];
            float4 b4 = *(const float4*)&Bs[kk][tx * 4];
            float a[4] = {a4.x, a4.y, a4.z, a4.w};
            float b[4] = {b4.x, b4.y, b4.z, b4.w};
            #pragma unroll
            for (int i = 0; i < 4; ++i)
                #pragma unroll
                for (int j = 0; j < 4; ++j)
                    acc[i][j] = fmaf(a[i], b[j], acc[i][j]);
        }
        __syncthreads();
    }

    // epilogue: leaky_relu, write float4 per row
    #pragma unroll
    for (int i = 0; i < 4; ++i) {
        int gr = row0 + ty * 4 + i;
        if (gr >= M) continue;
        float4 o;
        float v0 = acc[i][0], v1 = acc[i][1], v2 = acc[i][2], v3 = acc[i][3];
        o.x = v0 > 0.f ? v0 : LALPHA * v0;
        o.y = v1 > 0.f ? v1 : LALPHA * v1;
        o.z = v2 > 0.f ? v2 : LALPHA * v2;
        o.w = v3 > 0.f ? v3 : LALPHA * v3;
        *(float4*)(out + (size_t)gr * 256 + col0 + tx * 4) = o;
    }
}

// ---------------------------------------------------------------------------
extern "C" void kernel_launch(void* const* d_in, const int* in_sizes, int n_in,
                              void* d_out, int out_size, void* d_ws, size_t ws_size,
                              hipStream_t stream) {
    const float* ebs0      = (const float*)d_in[0];
    const float* W_side_u  = (const float*)d_in[1];
    const float* W_dot_u   = (const float*)d_in[2];
    const float* W_side_i  = (const float*)d_in[3];
    const float* W_dot_i   = (const float*)d_in[4];
    const float* LI_vals_u = (const float*)d_in[5];
    const int*   LI_rows_u = (const int*)  d_in[6];
    const int*   LI_cols_u = (const int*)  d_in[7];
    const float* L_vals_u  = (const float*)d_in[8];
    const int*   L_rows_u  = (const int*)  d_in[9];
    const int*   L_cols_u  = (const int*)  d_in[10];
    const float* LI_vals_i = (const float*)d_in[11];
    const int*   LI_rows_i = (const int*)  d_in[12];
    const int*   LI_cols_i = (const int*)  d_in[13];
    const float* L_vals_i  = (const float*)d_in[14];
    const int*   L_rows_i  = (const int*)  d_in[15];
    const int*   L_cols_i  = (const int*)  d_in[16];

    float* out = (float*)d_out;
    float* ws  = (float*)d_ws;   // [50000, 512] fp32 = 102.4 MB

    const int nnz_LI_u = in_sizes[5];
    const int nnz_L_u  = in_sizes[8];
    const int nnz_LI_i = in_sizes[11];
    const int nnz_L_i  = in_sizes[14];

    dim3 sblock(256), sgrid((NUQ + 3) / 4);
    dim3 gblock(256), ggrid((NUQ + 63) / 64, 4);

    for (int l = 0; l < 2; ++l) {
        const float* src  = (l == 0) ? ebs0 : (out + (size_t)(l - 1) * NTOT * DQ);
        float*       outl = out + (size_t)l * NTOT * DQ;
        const size_t wofs = (size_t)l * 65536;  // 256*256 per layer

        // ---- entity u (rows [0, NU)) ----
        spmm_kernel<<<sgrid, sblock, 0, stream>>>(LI_rows_u, LI_cols_u, LI_vals_u,
                                                  nnz_LI_u, src, nullptr, ws, NUQ, 0);
        spmm_kernel<<<sgrid, sblock, 0, stream>>>(L_rows_u, L_cols_u, L_vals_u,
                                                  nnz_L_u, src, src, ws, NUQ, 256);
        gemm_leaky_kernel<<<ggrid, gblock, 0, stream>>>(ws, W_side_u + wofs,
                                                        W_dot_u + wofs, outl, NUQ);

        // ---- entity i (rows [NU, N)) ----
        spmm_kernel<<<sgrid, sblock, 0, stream>>>(LI_rows_i, LI_cols_i, LI_vals_i,
                                                  nnz_LI_i, src, nullptr, ws, NIQ, 0);
        spmm_kernel<<<sgrid, sblock, 0, stream>>>(L_rows_i, L_cols_i, L_vals_i,
                                                  nnz_L_i, src, src + (size_t)NUQ * DQ, ws, NIQ, 256);
        gemm_leaky_kernel<<<ggrid, gblock, 0, stream>>>(ws, W_side_i + wofs,
                                                        W_dot_i + wofs, outl + (size_t)NUQ * DQ, NIQ);
    }
}

// Round 2
// 1535.946 us; speedup vs baseline: 1.3240x; 1.3240x over previous
//
#include <hip/hip_runtime.h>

#define NUQ 50000
#define NIQ 50000
#define DQ 256
#define NTOT 100000
#define LALPHA 0.2f

// ---------------------------------------------------------------------------
// Build CSR row_ptr from sorted rows[] (one thread per nnz boundary).
// rptr[r] = first index e with rows[e] >= r ; rptr[n_rows] = nnz.
// ---------------------------------------------------------------------------
__global__ __launch_bounds__(256) void build_rowptr(
    const int* __restrict__ rows, int nnz, int* __restrict__ rptr, int n_rows)
{
    int e = blockIdx.x * 256 + threadIdx.x;
    if (e > nnz) return;
    int prev = (e == 0)   ? -1     : rows[e - 1];
    int cur  = (e == nnz) ? n_rows : rows[e];
    for (int r = prev + 1; r <= cur; ++r) rptr[r] = e;
}

// ---------------------------------------------------------------------------
// Dual SpMM: blockIdx.y = 0 -> LI matrix into ws cols [0,256)
//            blockIdx.y = 1 -> L  matrix, * ebs slice, into ws cols [256,512)
// One wave per row; lane covers 4 dims (float4). Gather loop unrolled x4 so
// 4 x 1KB gathers are in flight per wave.
// ---------------------------------------------------------------------------
__global__ __launch_bounds__(256) void spmm_dual(
    const int* __restrict__ rptrA, const int* __restrict__ colsA, const float* __restrict__ valsA,
    const int* __restrict__ rptrB, const int* __restrict__ colsB, const float* __restrict__ valsB,
    const float* __restrict__ src,   // [NTOT, 256] current ebs
    const float* __restrict__ mul,   // [n_rows, 256] ebs slice for this entity
    float* __restrict__ out,         // [n_rows, 512] scratch
    int n_rows)
{
    const int wave = threadIdx.x >> 6;
    const int lane = threadIdx.x & 63;
    const int row  = blockIdx.x * 4 + wave;
    if (row >= n_rows) return;
    const bool isB = (blockIdx.y != 0);

    const int*   rptr = isB ? rptrB : rptrA;
    const int*   cols = isB ? colsB : colsA;
    const float* vals = isB ? valsB : valsA;

    const int start = rptr[row];
    const int end   = rptr[row + 1];

    // independent load, overlaps with the gather loop
    float4 m = {1.f, 1.f, 1.f, 1.f};
    if (isB) m = ((const float4*)(mul + (size_t)row * DQ))[lane];

    float4 acc = {0.f, 0.f, 0.f, 0.f};
    int e = start;
    for (; e + 4 <= end; e += 4) {
        int   c0 = cols[e], c1 = cols[e + 1], c2 = cols[e + 2], c3 = cols[e + 3];
        float v0 = vals[e], v1 = vals[e + 1], v2 = vals[e + 2], v3 = vals[e + 3];
        float4 s0 = ((const float4*)(src + (size_t)c0 * DQ))[lane];
        float4 s1 = ((const float4*)(src + (size_t)c1 * DQ))[lane];
        float4 s2 = ((const float4*)(src + (size_t)c2 * DQ))[lane];
        float4 s3 = ((const float4*)(src + (size_t)c3 * DQ))[lane];
        acc.x = fmaf(v0, s0.x, acc.x); acc.y = fmaf(v0, s0.y, acc.y);
        acc.z = fmaf(v0, s0.z, acc.z); acc.w = fmaf(v0, s0.w, acc.w);
        acc.x = fmaf(v1, s1.x, acc.x); acc.y = fmaf(v1, s1.y, acc.y);
        acc.z = fmaf(v1, s1.z, acc.z); acc.w = fmaf(v1, s1.w, acc.w);
        acc.x = fmaf(v2, s2.x, acc.x); acc.y = fmaf(v2, s2.y, acc.y);
        acc.z = fmaf(v2, s2.z, acc.z); acc.w = fmaf(v2, s2.w, acc.w);
        acc.x = fmaf(v3, s3.x, acc.x); acc.y = fmaf(v3, s3.y, acc.y);
        acc.z = fmaf(v3, s3.z, acc.z); acc.w = fmaf(v3, s3.w, acc.w);
    }
    for (; e < end; ++e) {
        int   c = cols[e];
        float v = vals[e];
        float4 s = ((const float4*)(src + (size_t)c * DQ))[lane];
        acc.x = fmaf(v, s.x, acc.x); acc.y = fmaf(v, s.y, acc.y);
        acc.z = fmaf(v, s.z, acc.z); acc.w = fmaf(v, s.w, acc.w);
    }
    acc.x *= m.x; acc.y *= m.y; acc.z *= m.z; acc.w *= m.w;
    ((float4*)(out + (size_t)row * 512 + (isB ? 256 : 0)))[lane] = acc;
}

// ---------------------------------------------------------------------------
// Fused GEMM + leaky_relu:  out[M,256] = leaky( A[M,512] @ [Ws;Wd][512,256] )
// BM=64, BN=256, BK=16; 256 threads; micro-tile 4 rows x 16 cols (4 blocks
// of 4). A fetched once per GEMM. All LDS access <=2-way (free on CDNA4).
// ---------------------------------------------------------------------------
__global__ __launch_bounds__(256) void gemm_leaky_kernel(
    const float* __restrict__ A,    // [M, 512] row-major scratch
    const float* __restrict__ Ws,   // [256,256] row-major (k 0..255)
    const float* __restrict__ Wd,   // [256,256] row-major (k 256..511)
    float* __restrict__ out,        // [M, 256]
    int M)
{
    __shared__ float As[16][64];    // [k][m]
    __shared__ float Bs[16][256];   // [k][n]

    const int tid  = threadIdx.x;
    const int ty   = tid >> 4;      // 0..15 -> rows ty*4..+3
    const int tx   = tid & 15;      // 0..15 -> cols tx*4 + {0,64,128,192}
    const int row0 = blockIdx.x * 64;

    // staging indices
    const int s_ar = tid & 63;      // A row within tile
    const int s_ak = (tid >> 6) * 4;// A k offset (0,4,8,12)
    const int s_bk = tid >> 4;      // B k within tile (0..15)
    const int s_bc = (tid & 15) * 4;// B col base (0..60)

    float acc[4][16] = {};

    const int arow = row0 + s_ar;
    const float* Arow = A + (size_t)arow * 512;

    for (int kt = 0; kt < 32; ++kt) {
        const int k0 = kt * 16;

        // stage A tile transposed: 1 float4 per thread, 2-way bank (free)
        float4 av = {0.f, 0.f, 0.f, 0.f};
        if (arow < M) av = *(const float4*)(Arow + k0 + s_ak);
        As[s_ak + 0][s_ar] = av.x;
        As[s_ak + 1][s_ar] = av.y;
        As[s_ak + 2][s_ar] = av.z;
        As[s_ak + 3][s_ar] = av.w;

        // stage B tile: 4 float4 per thread
        const float* Bbase = (k0 < 256) ? (Ws + (size_t)k0 * 256)
                                        : (Wd + (size_t)(k0 - 256) * 256);
        const float* Brow = Bbase + (size_t)s_bk * 256;
        #pragma unroll
        for (int j = 0; j < 4; ++j)
            *(float4*)&Bs[s_bk][s_bc + j * 64] = *(const float4*)(Brow + s_bc + j * 64);

        __syncthreads();

        #pragma unroll
        for (int kk = 0; kk < 16; ++kk) {
            float4 a4 = *(const float4*)&As[kk][ty * 4];
            float a[4] = {a4.x, a4.y, a4.z, a4.w};
            #pragma unroll
            for (int j = 0; j < 4; ++j) {
                float4 b4 = *(const float4*)&Bs[kk][tx * 4 + j * 64];
                float b[4] = {b4.x, b4.y, b4.z, b4.w};
                #pragma unroll
                for (int i = 0; i < 4; ++i) {
                    acc[i][j * 4 + 0] = fmaf(a[i], b[0], acc[i][j * 4 + 0]);
                    acc[i][j * 4 + 1] = fmaf(a[i], b[1], acc[i][j * 4 + 1]);
                    acc[i][j * 4 + 2] = fmaf(a[i], b[2], acc[i][j * 4 + 2]);
                    acc[i][j * 4 + 3] = fmaf(a[i], b[3], acc[i][j * 4 + 3]);
                }
            }
        }
        __syncthreads();
    }

    // epilogue: leaky_relu, float4 stores
    #pragma unroll
    for (int i = 0; i < 4; ++i) {
        int gr = row0 + ty * 4 + i;
        if (gr >= M) continue;
        float* orow = out + (size_t)gr * 256;
        #pragma unroll
        for (int j = 0; j < 4; ++j) {
            float v0 = acc[i][j * 4 + 0], v1 = acc[i][j * 4 + 1];
            float v2 = acc[i][j * 4 + 2], v3 = acc[i][j * 4 + 3];
            float4 o;
            o.x = v0 > 0.f ? v0 : LALPHA * v0;
            o.y = v1 > 0.f ? v1 : LALPHA * v1;
            o.z = v2 > 0.f ? v2 : LALPHA * v2;
            o.w = v3 > 0.f ? v3 : LALPHA * v3;
            *(float4*)(orow + tx * 4 + j * 64) = o;
        }
    }
}

// ---------------------------------------------------------------------------
extern "C" void kernel_launch(void* const* d_in, const int* in_sizes, int n_in,
                              void* d_out, int out_size, void* d_ws, size_t ws_size,
                              hipStream_t stream) {
    const float* ebs0      = (const float*)d_in[0];
    const float* W_side_u  = (const float*)d_in[1];
    const float* W_dot_u   = (const float*)d_in[2];
    const float* W_side_i  = (const float*)d_in[3];
    const float* W_dot_i   = (const float*)d_in[4];
    const float* LI_vals_u = (const float*)d_in[5];
    const int*   LI_rows_u = (const int*)  d_in[6];
    const int*   LI_cols_u = (const int*)  d_in[7];
    const float* L_vals_u  = (const float*)d_in[8];
    const int*   L_rows_u  = (const int*)  d_in[9];
    const int*   L_cols_u  = (const int*)  d_in[10];
    const float* LI_vals_i = (const float*)d_in[11];
    const int*   LI_rows_i = (const int*)  d_in[12];
    const int*   LI_cols_i = (const int*)  d_in[13];
    const float* L_vals_i  = (const float*)d_in[14];
    const int*   L_rows_i  = (const int*)  d_in[15];
    const int*   L_cols_i  = (const int*)  d_in[16];

    float* out = (float*)d_out;
    float* ws  = (float*)d_ws;

    // ws layout: A-scratch [50000, 512] fp32 = 102,400,000 B, then 4 row_ptr
    // arrays of 50001 ints each (800,016 B). Total ~103.2 MB.
    int* rp_LI_u = (int*)((char*)d_ws + 102400000);
    int* rp_L_u  = rp_LI_u + 50001;
    int* rp_LI_i = rp_L_u  + 50001;
    int* rp_L_i  = rp_LI_i + 50001;

    const int nnz_LI_u = in_sizes[5];
    const int nnz_L_u  = in_sizes[8];
    const int nnz_LI_i = in_sizes[11];
    const int nnz_L_i  = in_sizes[14];

    // build row_ptr once per launch (ws is re-poisoned before every call)
    {
        dim3 b(256);
        build_rowptr<<<dim3((nnz_LI_u + 256) / 256), b, 0, stream>>>(LI_rows_u, nnz_LI_u, rp_LI_u, NUQ);
        build_rowptr<<<dim3((nnz_L_u  + 256) / 256), b, 0, stream>>>(L_rows_u,  nnz_L_u,  rp_L_u,  NUQ);
        build_rowptr<<<dim3((nnz_LI_i + 256) / 256), b, 0, stream>>>(LI_rows_i, nnz_LI_i, rp_LI_i, NIQ);
        build_rowptr<<<dim3((nnz_L_i  + 256) / 256), b, 0, stream>>>(L_rows_i,  nnz_L_i,  rp_L_i,  NIQ);
    }

    dim3 sblock(256), sgrid((NUQ + 3) / 4, 2);
    dim3 gblock(256), ggrid((NUQ + 63) / 64);

    for (int l = 0; l < 2; ++l) {
        const float* src  = (l == 0) ? ebs0 : (out + (size_t)(l - 1) * NTOT * DQ);
        float*       outl = out + (size_t)l * NTOT * DQ;
        const size_t wofs = (size_t)l * 65536;  // 256*256 per layer

        // ---- entity u (rows [0, NU)) ----
        spmm_dual<<<sgrid, sblock, 0, stream>>>(rp_LI_u, LI_cols_u, LI_vals_u,
                                                rp_L_u,  L_cols_u,  L_vals_u,
                                                src, src, ws, NUQ);
        gemm_leaky_kernel<<<ggrid, gblock, 0, stream>>>(ws, W_side_u + wofs,
                                                        W_dot_u + wofs, outl, NUQ);

        // ---- entity i (rows [NU, N)) ----
        spmm_dual<<<sgrid, sblock, 0, stream>>>(rp_LI_i, LI_cols_i, LI_vals_i,
                                                rp_L_i,  L_cols_i,  L_vals_i,
                                                src, src + (size_t)NUQ * DQ, ws, NIQ);
        gemm_leaky_kernel<<<ggrid, gblock, 0, stream>>>(ws, W_side_i + wofs,
                                                        W_dot_i + wofs, outl + (size_t)NUQ * DQ, NIQ);
    }
}

// Round 3
// 767.922 us; speedup vs baseline: 2.6481x; 2.0001x over previous
//
#include <hip/hip_runtime.h>

#define NUQ 50000
#define NIQ 50000
#define DQ 256
#define NTOT 100000
#define LALPHA 0.2f

typedef __attribute__((ext_vector_type(8))) __bf16 bf16x8;
typedef __attribute__((ext_vector_type(4))) float floatx4;

__device__ __forceinline__ float b2f(unsigned short u) {
    unsigned int x = ((unsigned int)u) << 16;
    return __builtin_bit_cast(float, x);
}
__device__ __forceinline__ unsigned short f2b(float f) {
    unsigned int u = __builtin_bit_cast(unsigned int, f);
    u = u + 0x7FFFu + ((u >> 16) & 1u);   // round-to-nearest-even
    return (unsigned short)(u >> 16);
}

#define GLD_LDS16(g, l)                                                        \
    __builtin_amdgcn_global_load_lds(                                          \
        (const __attribute__((address_space(1))) void*)(g),                    \
        (__attribute__((address_space(3))) void*)(l), 16, 0, 0)

// ---------------------------------------------------------------------------
// CSR row_ptr from sorted rows[].
// ---------------------------------------------------------------------------
__global__ __launch_bounds__(256) void build_rowptr(
    const int* __restrict__ rows, int nnz, int* __restrict__ rptr, int n_rows)
{
    int e = blockIdx.x * 256 + threadIdx.x;
    if (e > nnz) return;
    int prev = (e == 0)   ? -1     : rows[e - 1];
    int cur  = (e == nnz) ? n_rows : rows[e];
    for (int r = prev + 1; r <= cur; ++r) rptr[r] = e;
}

// ---------------------------------------------------------------------------
// fp32 -> bf16 (RNE), vectorized. n4 = element_count / 4.
// ---------------------------------------------------------------------------
__global__ __launch_bounds__(256) void cvt_f32_bf16(
    const float* __restrict__ in, unsigned short* __restrict__ out, int n4)
{
    int i = blockIdx.x * 256 + threadIdx.x;
    if (i >= n4) return;
    float4 v = ((const float4*)in)[i];
    ushort4 o;
    o.x = f2b(v.x); o.y = f2b(v.y); o.z = f2b(v.z); o.w = f2b(v.w);
    ((ushort4*)out)[i] = o;
}

// ---------------------------------------------------------------------------
// Build Bt[4][256][512] bf16: Bt[l*2+e][n][k] = (k<256 ? Wside : Wdot)[l][k%256][n]
// k fastest across threads -> coalesced writes; W is tiny (2 MB), L2-cached.
// ---------------------------------------------------------------------------
__global__ __launch_bounds__(256) void build_bt(
    const float* __restrict__ Ws_u, const float* __restrict__ Wd_u,
    const float* __restrict__ Ws_i, const float* __restrict__ Wd_i,
    unsigned short* __restrict__ Bt)
{
    int idx = blockIdx.x * 256 + threadIdx.x;    // 4*256*512 total
    int k   = idx & 511;
    int n   = (idx >> 9) & 255;
    int buf = idx >> 17;                          // l*2 + e
    int l = buf >> 1, e = buf & 1;
    const float* Wside = e ? Ws_i : Ws_u;
    const float* Wdot  = e ? Wd_i : Wd_u;
    float v = (k < 256) ? Wside[((size_t)l * 256 + k)       * 256 + n]
                        : Wdot [((size_t)l * 256 + (k-256)) * 256 + n];
    Bt[idx] = f2b(v);
}

// ---------------------------------------------------------------------------
// Dual SpMM (bf16 gather, fp32 accumulate, bf16 store):
//   y=0 -> LI into A cols [0,256) ; y=1 -> L * ebs-slice into cols [256,512)
// One wave per row; lane covers 4 dims (ushort4 = 8B gathers).
// ---------------------------------------------------------------------------
__global__ __launch_bounds__(256) void spmm_dual_bf16(
    const int* __restrict__ rptrA, const int* __restrict__ colsA, const float* __restrict__ valsA,
    const int* __restrict__ rptrB, const int* __restrict__ colsB, const float* __restrict__ valsB,
    const unsigned short* __restrict__ src,  // [NTOT,256] bf16
    const unsigned short* __restrict__ mul,  // [n_rows,256] bf16 entity slice
    unsigned short* __restrict__ out,        // [n_rows,512] bf16
    int n_rows)
{
    const int wave = threadIdx.x >> 6;
    const int lane = threadIdx.x & 63;
    const int row  = blockIdx.x * 4 + wave;
    if (row >= n_rows) return;
    const bool isB = (blockIdx.y != 0);

    const int*   rptr = isB ? rptrB : rptrA;
    const int*   cols = isB ? colsB : colsA;
    const float* vals = isB ? valsB : valsA;

    const int start = rptr[row];
    const int end   = rptr[row + 1];

    ushort4 mraw = {0, 0, 0, 0};
    if (isB) mraw = ((const ushort4*)(mul + (size_t)row * DQ))[lane];

    float ax = 0.f, ay = 0.f, az = 0.f, aw = 0.f;
    int e = start;
    for (; e + 4 <= end; e += 4) {
        int   c0 = cols[e],     c1 = cols[e + 1], c2 = cols[e + 2], c3 = cols[e + 3];
        float v0 = vals[e],     v1 = vals[e + 1], v2 = vals[e + 2], v3 = vals[e + 3];
        ushort4 s0 = ((const ushort4*)(src + (size_t)c0 * DQ))[lane];
        ushort4 s1 = ((const ushort4*)(src + (size_t)c1 * DQ))[lane];
        ushort4 s2 = ((const ushort4*)(src + (size_t)c2 * DQ))[lane];
        ushort4 s3 = ((const ushort4*)(src + (size_t)c3 * DQ))[lane];
        ax = fmaf(v0, b2f(s0.x), ax); ay = fmaf(v0, b2f(s0.y), ay);
        az = fmaf(v0, b2f(s0.z), az); aw = fmaf(v0, b2f(s0.w), aw);
        ax = fmaf(v1, b2f(s1.x), ax); ay = fmaf(v1, b2f(s1.y), ay);
        az = fmaf(v1, b2f(s1.z), az); aw = fmaf(v1, b2f(s1.w), aw);
        ax = fmaf(v2, b2f(s2.x), ax); ay = fmaf(v2, b2f(s2.y), ay);
        az = fmaf(v2, b2f(s2.z), az); aw = fmaf(v2, b2f(s2.w), aw);
        ax = fmaf(v3, b2f(s3.x), ax); ay = fmaf(v3, b2f(s3.y), ay);
        az = fmaf(v3, b2f(s3.z), az); aw = fmaf(v3, b2f(s3.w), aw);
    }
    for (; e < end; ++e) {
        int   c = cols[e];
        float v = vals[e];
        ushort4 s = ((const ushort4*)(src + (size_t)c * DQ))[lane];
        ax = fmaf(v, b2f(s.x), ax); ay = fmaf(v, b2f(s.y), ay);
        az = fmaf(v, b2f(s.z), az); aw = fmaf(v, b2f(s.w), aw);
    }
    if (isB) {
        ax *= b2f(mraw.x); ay *= b2f(mraw.y);
        az *= b2f(mraw.z); aw *= b2f(mraw.w);
    }
    ushort4 o;
    o.x = f2b(ax); o.y = f2b(ay); o.z = f2b(az); o.w = f2b(aw);
    ((ushort4*)(out + (size_t)row * 512 + (isB ? 256 : 0)))[lane] = o;
}

// ---------------------------------------------------------------------------
// MFMA GEMM + leaky_relu: out[M,256] = leaky( A[M,512]bf16 @ Bt^T )
//   Bt is [256 n][512 k] bf16 (pre-transposed weights).
// 128x128 tile, BK=32, 4 waves (2x2 of 64x64), 16x16x32 MFMA, fp32 accum.
// Staging via global_load_lds width=16; LDS layout chosen so both staging
// (base + lane*16) and fragment reads (base + lane*16) are linear.
// ---------------------------------------------------------------------------
__global__ __launch_bounds__(256) void gemm_mfma_leaky(
    const unsigned short* __restrict__ A,   // [M,512] bf16
    const unsigned short* __restrict__ Bt,  // [256,512] bf16
    float* __restrict__ out,                // [M,256] (already offset)
    int M)
{
    __shared__ unsigned short As[4096];     // 8 KB  [(m>>4)][kblk][m&15][8]
    __shared__ unsigned short Bs[4096];     // 8 KB  same scheme over n

    const int tid  = threadIdx.x;
    const int lane = tid & 63;
    const int w    = tid >> 6;              // wave 0..3
    const int row0 = blockIdx.x * 128;
    const int n0   = blockIdx.y * 128;

    const int m_off = (w & 1) * 64;
    const int n_off = (w >> 1) * 64;

    floatx4 acc[4][4] = {};

    // staging addresses: chunk c = w*2+j covers linear t = c*64+lane in [0,512)
    // t decodes: m = ((t>>6)<<4)|(t&15), kblk = (t>>4)&3  (8 bf16 per kblk)
    const unsigned short* gA[2];
    const unsigned short* gB[2];
    int ldsoff[2];
    #pragma unroll
    for (int j = 0; j < 2; ++j) {
        int c = w * 2 + j;
        int t = c * 64 + lane;
        int m    = ((t >> 6) << 4) | (t & 15);
        int kblk = (t >> 4) & 3;
        int gr = row0 + m; if (gr >= M) gr = M - 1;      // clamp (safe garbage)
        gA[j] = A  + (size_t)gr * 512 + kblk * 8;
        gB[j] = Bt + (size_t)(n0 + m) * 512 + kblk * 8;  // n always in range
        ldsoff[j] = c * 512;                             // shorts
    }

    const int lr = lane >> 4;      // 0..3
    const int lc = lane & 15;

    for (int kt = 0; kt < 16; ++kt) {
        const int k0 = kt * 32;
        #pragma unroll
        for (int j = 0; j < 2; ++j) {
            GLD_LDS16(gA[j] + k0, &As[ldsoff[j]]);
            GLD_LDS16(gB[j] + k0, &Bs[ldsoff[j]]);
        }
        __syncthreads();

        bf16x8 af[4], bfr[4];
        #pragma unroll
        for (int tm = 0; tm < 4; ++tm)
            af[tm] = *(const bf16x8*)&As[((m_off >> 4) + tm) * 512 + lr * 128 + lc * 8];
        #pragma unroll
        for (int tn = 0; tn < 4; ++tn)
            bfr[tn] = *(const bf16x8*)&Bs[((n_off >> 4) + tn) * 512 + lr * 128 + lc * 8];

        #pragma unroll
        for (int tm = 0; tm < 4; ++tm)
            #pragma unroll
            for (int tn = 0; tn < 4; ++tn)
                acc[tm][tn] = __builtin_amdgcn_mfma_f32_16x16x32_bf16(
                    af[tm], bfr[tn], acc[tm][tn], 0, 0, 0);

        __syncthreads();
    }

    // epilogue: C/D layout col=lane&15, row=(lane>>4)*4+r  [verified m89/m91]
    #pragma unroll
    for (int tm = 0; tm < 4; ++tm) {
        #pragma unroll
        for (int r = 0; r < 4; ++r) {
            int gr = row0 + m_off + tm * 16 + lr * 4 + r;
            if (gr >= M) continue;
            float* orow = out + (size_t)gr * 256;
            #pragma unroll
            for (int tn = 0; tn < 4; ++tn) {
                int gc = n0 + n_off + tn * 16 + lc;
                float v = acc[tm][tn][r];
                orow[gc] = v > 0.f ? v : LALPHA * v;
            }
        }
    }
}

// ---------------------------------------------------------------------------
extern "C" void kernel_launch(void* const* d_in, const int* in_sizes, int n_in,
                              void* d_out, int out_size, void* d_ws, size_t ws_size,
                              hipStream_t stream) {
    const float* ebs0      = (const float*)d_in[0];
    const float* W_side_u  = (const float*)d_in[1];
    const float* W_dot_u   = (const float*)d_in[2];
    const float* W_side_i  = (const float*)d_in[3];
    const float* W_dot_i   = (const float*)d_in[4];
    const float* LI_vals_u = (const float*)d_in[5];
    const int*   LI_rows_u = (const int*)  d_in[6];
    const int*   LI_cols_u = (const int*)  d_in[7];
    const float* L_vals_u  = (const float*)d_in[8];
    const int*   L_rows_u  = (const int*)  d_in[9];
    const int*   L_cols_u  = (const int*)  d_in[10];
    const float* LI_vals_i = (const float*)d_in[11];
    const int*   LI_rows_i = (const int*)  d_in[12];
    const int*   LI_cols_i = (const int*)  d_in[13];
    const float* L_vals_i  = (const float*)d_in[14];
    const int*   L_rows_i  = (const int*)  d_in[15];
    const int*   L_cols_i  = (const int*)  d_in[16];

    float* out = (float*)d_out;

    // ws layout (bytes):
    //   [0, 51.2M)        A-scratch  [50000,512] bf16
    //   [51.2M, 102.4M)   ebs_bf16   [100000,256] bf16
    //   [102.4M, +1M)     Bt         [4][256][512] bf16
    //   [.., +0.8M)       rptr x4
    unsigned short* Abuf   = (unsigned short*)d_ws;
    unsigned short* ebs_bf = (unsigned short*)((char*)d_ws + 51200000);
    unsigned short* Bt     = (unsigned short*)((char*)d_ws + 102400000);
    int* rp_LI_u = (int*)((char*)d_ws + 103448576);
    int* rp_L_u  = rp_LI_u + 50001;
    int* rp_LI_i = rp_L_u  + 50001;
    int* rp_L_i  = rp_LI_i + 50001;

    const int nnz_LI_u = in_sizes[5];
    const int nnz_L_u  = in_sizes[8];
    const int nnz_LI_i = in_sizes[11];
    const int nnz_L_i  = in_sizes[14];

    dim3 b256(256);
    build_rowptr<<<dim3((nnz_LI_u + 256) / 256), b256, 0, stream>>>(LI_rows_u, nnz_LI_u, rp_LI_u, NUQ);
    build_rowptr<<<dim3((nnz_L_u  + 256) / 256), b256, 0, stream>>>(L_rows_u,  nnz_L_u,  rp_L_u,  NUQ);
    build_rowptr<<<dim3((nnz_LI_i + 256) / 256), b256, 0, stream>>>(LI_rows_i, nnz_LI_i, rp_LI_i, NIQ);
    build_rowptr<<<dim3((nnz_L_i  + 256) / 256), b256, 0, stream>>>(L_rows_i,  nnz_L_i,  rp_L_i,  NIQ);
    build_bt<<<dim3(2048), b256, 0, stream>>>(W_side_u, W_dot_u, W_side_i, W_dot_i, Bt);
    cvt_f32_bf16<<<dim3(25000), b256, 0, stream>>>(ebs0, ebs_bf, NTOT * DQ / 4);

    dim3 sgrid((NUQ + 3) / 4, 2);
    dim3 ggrid((NUQ + 127) / 128, 2);

    for (int l = 0; l < 2; ++l) {
        float* outl = out + (size_t)l * NTOT * DQ;

        // ---- entity u ----
        spmm_dual_bf16<<<sgrid, b256, 0, stream>>>(rp_LI_u, LI_cols_u, LI_vals_u,
                                                   rp_L_u,  L_cols_u,  L_vals_u,
                                                   ebs_bf, ebs_bf, Abuf, NUQ);
        gemm_mfma_leaky<<<ggrid, b256, 0, stream>>>(Abuf, Bt + (size_t)(l * 2 + 0) * 131072,
                                                    outl, NUQ);
        // ---- entity i ----
        spmm_dual_bf16<<<sgrid, b256, 0, stream>>>(rp_LI_i, LI_cols_i, LI_vals_i,
                                                   rp_L_i,  L_cols_i,  L_vals_i,
                                                   ebs_bf, ebs_bf + (size_t)NUQ * DQ, Abuf, NIQ);
        gemm_mfma_leaky<<<ggrid, b256, 0, stream>>>(Abuf, Bt + (size_t)(l * 2 + 1) * 131072,
                                                    outl + (size_t)NUQ * DQ, NIQ);

        // next layer's SpMM input: bf16 copy of this layer's fp32 output
        if (l == 0)
            cvt_f32_bf16<<<dim3(25000), b256, 0, stream>>>(outl, ebs_bf, NTOT * DQ / 4);
    }
}